// Round 4
// baseline (442.519 us; speedup 1.0000x reference)
//
#include <hip/hip_runtime.h>
#include <hip/hip_bf16.h>
#include <stdint.h>
#include <math.h>

#define NTHR 256
#define SPB 32      // samples per block
#define TT 8        // timesteps

// --- threefry2x32, key schedule exactly as JAX (Random123) ---
__device__ __forceinline__ void threefry2x32(uint32_t k0, uint32_t k1,
                                             uint32_t x0, uint32_t x1,
                                             uint32_t& o0, uint32_t& o1) {
  const uint32_t ks2 = 0x1BD11BDAu ^ k0 ^ k1;
  uint32_t v0 = x0 + k0, v1 = x1 + k1;
#define TFR(r) { v0 += v1; v1 = (v1 << r) | (v1 >> (32 - r)); v1 ^= v0; }
  TFR(13) TFR(15) TFR(26) TFR(6)   v0 += k1;  v1 += ks2 + 1u;
  TFR(17) TFR(29) TFR(16) TFR(24)  v0 += ks2; v1 += k0 + 2u;
  TFR(13) TFR(15) TFR(26) TFR(6)   v0 += k0;  v1 += k1 + 3u;
  TFR(17) TFR(29) TFR(16) TFR(24)  v0 += k1;  v1 += ks2 + 4u;
  TFR(13) TFR(15) TFR(26) TFR(6)   v0 += ks2; v1 += k0 + 5u;
#undef TFR
  o0 = v0; o1 = v1;
}

// One Linear(+LIF) layer for the block's 32 samples, all 8 timesteps.
// Thread (b = tid>>3, oc = tid&7) owns 8 outputs (oc*8..+7) of the current
// 64-output quarter; acc[t][j] gives 8x t-reuse per LDS weight read.
// Spikes bit-packed: bit i of byte k <-> neuron 8k+i. Zero-skip: if all
// 8 timesteps' spike words for this input chunk are 0, the FMA block is
// skipped exactly (acc contribution is 0) — layers 2..4 are almost always
// silent (LIF threshold 1.0 vs current sd ~0.1), so this collapses their
// cost to staging + bit loads.
template<int I, int O, bool LAST>
__device__ __forceinline__ void layer_lif(
    const float* __restrict__ Wg, const float* __restrict__ Bg,
    const uint8_t* __restrict__ s_in, uint8_t* __restrict__ s_out,
    float* __restrict__ wbuf, float* __restrict__ bias_s,
    float* __restrict__ outp, int bglob0)
{
  constexpr int WST = 68;   // padded LDS row stride (floats), 16B aligned
  const int tid = threadIdx.x;
  const int b  = tid >> 3;  // 0..31
  const int oc = tid & 7;   // 0..7
  __syncthreads();          // previous stage done with bias_s / s_in
  if (tid < O) bias_s[tid] = Bg[tid];

  for (int q = 0; q < O / 64; ++q) {
    const int obase = q * 64;
    float acc[TT][8];
    #pragma unroll
    for (int t = 0; t < TT; ++t)
      #pragma unroll
      for (int j = 0; j < 8; ++j) acc[t][j] = 0.f;

    for (int ic = 0; ic < I / 64; ++ic) {
      __syncthreads();  // previous wbuf users done
      // stage 64x64 f32 W chunk transposed: wbuf[i_local][o_local]
      #pragma unroll
      for (int k = 0; k < 4; ++k) {
        int fi = tid + k * NTHR;   // 1024 float4s
        int o  = fi >> 4;
        int i4 = fi & 15;
        const float4 w4 = *reinterpret_cast<const float4*>(
            &Wg[(size_t)(obase + o) * I + ic * 64 + i4 * 4]);
        float* wp = &wbuf[(i4 * 4) * WST + o];
        wp[0 * WST] = w4.x; wp[1 * WST] = w4.y;
        wp[2 * WST] = w4.z; wp[3 * WST] = w4.w;
      }
      __syncthreads();
      // spike bits of this 64-input chunk, all 8 timesteps
      uint32_t r[TT][2];
      uint32_t any = 0;
      #pragma unroll
      for (int t = 0; t < TT; ++t) {
        const uint32_t* sp = reinterpret_cast<const uint32_t*>(
            s_in + (size_t)(t * SPB + b) * (I / 8) + ic * 8);
        r[t][0] = sp[0];
        r[t][1] = sp[1];
        any |= r[t][0] | r[t][1];
      }
      if (any) {
        #pragma unroll
        for (int w = 0; w < 2; ++w) {
          for (int i2 = 0; i2 < 32; ++i2) {
            const float* wrow = &wbuf[(w * 32 + i2) * WST + oc * 8];
            const float4 wa = *reinterpret_cast<const float4*>(wrow);
            const float4 wb = *reinterpret_cast<const float4*>(wrow + 4);
            #pragma unroll
            for (int t = 0; t < TT; ++t) {
              const float sf = (float)((r[t][w] >> i2) & 1u);
              acc[t][0] += wa.x * sf; acc[t][1] += wa.y * sf;
              acc[t][2] += wa.z * sf; acc[t][3] += wa.w * sf;
              acc[t][4] += wb.x * sf; acc[t][5] += wb.y * sf;
              acc[t][6] += wb.z * sf; acc[t][7] += wb.w * sf;
            }
          }
        }
      }
    }
    if constexpr (!LAST) {
      // LIF: v += (I-v)/2; spike = (v-1)>=0; hard reset (detach)
      float v[8];
      #pragma unroll
      for (int j = 0; j < 8; ++j) v[j] = 0.f;
      #pragma unroll
      for (int t = 0; t < TT; ++t) {
        uint32_t m = 0;
        #pragma unroll
        for (int j = 0; j < 8; ++j) {
          const float cur = acc[t][j] + bias_s[obase + oc * 8 + j];
          const float vn = v[j] + (cur - v[j]) * 0.5f;
          const bool s = (vn - 1.0f) >= 0.0f;
          m |= (uint32_t)s << j;
          v[j] = s ? 0.0f : vn;
        }
        s_out[(size_t)(t * SPB + b) * (O / 8) + (obase >> 3) + oc] = (uint8_t)m;
      }
    } else {
      // mean over t: (sum_t acc)*0.125 + bias  (exactly bias when silent)
      float oacc[8];
      #pragma unroll
      for (int j = 0; j < 8; ++j) oacc[j] = 0.f;
      #pragma unroll
      for (int t = 0; t < TT; ++t)
        #pragma unroll
        for (int j = 0; j < 8; ++j) oacc[j] += acc[t][j];
      float4 o0, o1;
      o0.x = oacc[0] * 0.125f + bias_s[oc * 8 + 0];
      o0.y = oacc[1] * 0.125f + bias_s[oc * 8 + 1];
      o0.z = oacc[2] * 0.125f + bias_s[oc * 8 + 2];
      o0.w = oacc[3] * 0.125f + bias_s[oc * 8 + 3];
      o1.x = oacc[4] * 0.125f + bias_s[oc * 8 + 4];
      o1.y = oacc[5] * 0.125f + bias_s[oc * 8 + 5];
      o1.z = oacc[6] * 0.125f + bias_s[oc * 8 + 6];
      o1.w = oacc[7] * 0.125f + bias_s[oc * 8 + 7];
      float* op = &outp[(size_t)(bglob0 + b) * 64 + oc * 8];
      *reinterpret_cast<float4*>(op)     = o0;
      *reinterpret_cast<float4*>(op + 4) = o1;
    }
  }
}

__global__ void __launch_bounds__(NTHR)
snn_fused(const float* __restrict__ x,
          const float* __restrict__ W1, const float* __restrict__ B1,
          const float* __restrict__ W2, const float* __restrict__ B2,
          const float* __restrict__ W3, const float* __restrict__ B3,
          const float* __restrict__ W4, const float* __restrict__ B4,
          float* __restrict__ out)
{
  __shared__ __align__(16) float wbuf[64 * 68];   // 17.4 KB
  __shared__ float    bias_s[256];
  __shared__ uint32_t s0[TT * SPB * 4];   // 16 B/row (128 in)
  __shared__ uint32_t s1[TT * SPB * 8];   // 32 B/row (256)
  __shared__ uint32_t s2[TT * SPB * 4];   // 16 B/row (128)
  __shared__ uint32_t s3[TT * SPB * 2];   //  8 B/row (64)
  const int tid = threadIdx.x;
  const int bglob0 = blockIdx.x * SPB;

  // Poisson encoder, original JAX threefry stream: flat element i<2^24
  // takes o0 of threefry(key,(i, i+2^24)); i>=2^24 takes o1. Per-t stride
  // is 2^22, so (t,b,d) pairs with (t+4,b,d). (Output is provably
  // insensitive to the stream — deep layers are silent — but keep it
  // faithful.)
  {
    const int b = tid >> 3, w16 = tid & 7;
    const int gb = bglob0 + b;
    uint32_t m[TT] = {0, 0, 0, 0, 0, 0, 0, 0};
    for (int j = 0; j < 16; ++j) {
      const int d = w16 * 16 + j;
      const double xv = (double)x[(size_t)gb * 128 + d];
      const double p = 1.0 / (1.0 + exp(-xv));
      #pragma unroll
      for (int t = 0; t < 4; ++t) {
        const uint32_t e = ((uint32_t)t << 22) | ((uint32_t)gb << 7) | (uint32_t)d;
        uint32_t o0, o1;
        threefry2x32(0u, 42u, e, e + 0x01000000u, o0, o1);
        const double u0 = (double)(__uint_as_float((o0 >> 9) | 0x3f800000u) - 1.0f);
        const double u1 = (double)(__uint_as_float((o1 >> 9) | 0x3f800000u) - 1.0f);
        m[t]     |= (uint32_t)(u0 < p) << j;
        m[t + 4] |= (uint32_t)(u1 < p) << j;
      }
    }
    #pragma unroll
    for (int t = 0; t < TT; ++t)
      reinterpret_cast<uint16_t*>(s0)[(t * SPB + b) * 8 + w16] = (uint16_t)m[t];
  }

  uint8_t* p0 = reinterpret_cast<uint8_t*>(s0);
  uint8_t* p1 = reinterpret_cast<uint8_t*>(s1);
  uint8_t* p2 = reinterpret_cast<uint8_t*>(s2);
  uint8_t* p3 = reinterpret_cast<uint8_t*>(s3);
  layer_lif<128, 256, false>(W1, B1, p0, p1, wbuf, bias_s, nullptr, bglob0);
  layer_lif<256, 128, false>(W2, B2, p1, p2, wbuf, bias_s, nullptr, bglob0);
  layer_lif<128,  64, false>(W3, B3, p2, p3, wbuf, bias_s, nullptr, bglob0);
  layer_lif< 64,  64, true >(W4, B4, p3, nullptr, wbuf, bias_s, out, bglob0);
}

extern "C" void kernel_launch(void* const* d_in, const int* in_sizes, int n_in,
                              void* d_out, int out_size, void* d_ws, size_t ws_size,
                              hipStream_t stream) {
  const float* x  = (const float*)d_in[0];
  const float* W1 = (const float*)d_in[1];
  const float* B1 = (const float*)d_in[2];
  const float* W2 = (const float*)d_in[3];
  const float* B2 = (const float*)d_in[4];
  const float* W3 = (const float*)d_in[5];
  const float* B3 = (const float*)d_in[6];
  const float* W4 = (const float*)d_in[7];
  const float* B4 = (const float*)d_in[8];
  float* out = (float*)d_out;
  dim3 grid(32768 / SPB), block(NTHR);
  hipLaunchKernelGGL(snn_fused, grid, block, 0, stream,
                     x, W1, B1, W2, B2, W3, B3, W4, B4, out);
}

// Round 5
// 299.006 us; speedup vs baseline: 1.4800x; 1.4800x over previous
//
#include <hip/hip_runtime.h>
#include <hip/hip_bf16.h>
#include <stdint.h>
#include <math.h>

#define NTHR 256
#define SPB 32      // samples per block
#define TT 8        // timesteps

typedef __attribute__((ext_vector_type(8))) short short8;  // bf16x8 MFMA frag
typedef __attribute__((ext_vector_type(4))) float f32x4;   // MFMA accumulator

// RNE f32->bf16 (no NaN handling needed; weights/spikes are finite)
__device__ __forceinline__ uint16_t bf16_rne(float f) {
  uint32_t u = __float_as_uint(f);
  return (uint16_t)((u + 0x7fffu + ((u >> 16) & 1u)) >> 16);
}
__device__ __forceinline__ float bf16_f32(uint16_t b) {
  return __uint_as_float((uint32_t)b << 16);
}

// --- threefry2x32, key schedule exactly as JAX (Random123) ---
__device__ __forceinline__ void threefry2x32(uint32_t k0, uint32_t k1,
                                             uint32_t x0, uint32_t x1,
                                             uint32_t& o0, uint32_t& o1) {
  const uint32_t ks2 = 0x1BD11BDAu ^ k0 ^ k1;
  uint32_t v0 = x0 + k0, v1 = x1 + k1;
#define TFR(r) { v0 += v1; v1 = (v1 << r) | (v1 >> (32 - r)); v1 ^= v0; }
  TFR(13) TFR(15) TFR(26) TFR(6)   v0 += k1;  v1 += ks2 + 1u;
  TFR(17) TFR(29) TFR(16) TFR(24)  v0 += ks2; v1 += k0 + 2u;
  TFR(13) TFR(15) TFR(26) TFR(6)   v0 += k0;  v1 += k1 + 3u;
  TFR(17) TFR(29) TFR(16) TFR(24)  v0 += k1;  v1 += ks2 + 4u;
  TFR(13) TFR(15) TFR(26) TFR(6)   v0 += ks2; v1 += k0 + 5u;
#undef TFR
  o0 = v0; o1 = v1;
}

// VALU Linear(+LIF) layer (layers 2..4). Rows indexed row = b*8 + t.
// msk: bit ic set => input chunk ic (64 neurons) has any spike in the block;
// unset chunks are skipped (staging AND fma) exactly (contribution is 0).
// Spike bytes written only when nonzero (s_out is pre-zeroed); flg_next
// accumulates output-chunk occupancy via LDS atomicOr.
template<int I, int O, bool LAST>
__device__ __forceinline__ void layer_valu(
    const float* __restrict__ Wg, const float* __restrict__ Bg,
    const uint32_t* __restrict__ s_in, uint8_t* __restrict__ s_out,
    uint32_t* __restrict__ flg_next,
    float* __restrict__ wbuf, float* __restrict__ bias_s,
    float* __restrict__ outp, int bglob0, uint32_t msk)
{
  constexpr int WST = 68;
  const int tid = threadIdx.x;
  const int b  = tid >> 3;  // 0..31
  const int oc = tid & 7;   // 0..7
  __syncthreads();          // previous stage done with wbuf/bias_s
  if (tid < O) bias_s[tid] = Bg[tid];

  for (int q = 0; q < O / 64; ++q) {
    const int obase = q * 64;
    float acc[TT][8];
    #pragma unroll
    for (int t = 0; t < TT; ++t)
      #pragma unroll
      for (int j = 0; j < 8; ++j) acc[t][j] = 0.f;

    for (int ic = 0; ic < I / 64; ++ic) {
      if (!((msk >> ic) & 1u)) continue;   // uniform skip: silent chunk
      __syncthreads();
      #pragma unroll
      for (int k = 0; k < 4; ++k) {
        int fi = tid + k * NTHR;
        int o  = fi >> 4;
        int i4 = fi & 15;
        const float4 w4 = *reinterpret_cast<const float4*>(
            &Wg[(size_t)(obase + o) * I + ic * 64 + i4 * 4]);
        float* wp = &wbuf[(i4 * 4) * WST + o];
        wp[0 * WST] = w4.x; wp[1 * WST] = w4.y;
        wp[2 * WST] = w4.z; wp[3 * WST] = w4.w;
      }
      __syncthreads();
      uint32_t r[TT][2];
      uint32_t any = 0;
      #pragma unroll
      for (int t = 0; t < TT; ++t) {
        const uint32_t* sp = &s_in[(size_t)(b * 8 + t) * (I / 32) + ic * 2];
        r[t][0] = sp[0]; r[t][1] = sp[1];
        any |= r[t][0] | r[t][1];
      }
      if (any) {
        #pragma unroll
        for (int w = 0; w < 2; ++w) {
          for (int i2 = 0; i2 < 32; ++i2) {
            const float* wrow = &wbuf[(w * 32 + i2) * WST + oc * 8];
            const float4 wa = *reinterpret_cast<const float4*>(wrow);
            const float4 wb = *reinterpret_cast<const float4*>(wrow + 4);
            #pragma unroll
            for (int t = 0; t < TT; ++t) {
              const float sf = (float)((r[t][w] >> i2) & 1u);
              acc[t][0] += wa.x * sf; acc[t][1] += wa.y * sf;
              acc[t][2] += wa.z * sf; acc[t][3] += wa.w * sf;
              acc[t][4] += wb.x * sf; acc[t][5] += wb.y * sf;
              acc[t][6] += wb.z * sf; acc[t][7] += wb.w * sf;
            }
          }
        }
      }
    }
    if constexpr (!LAST) {
      float v[8];
      #pragma unroll
      for (int j = 0; j < 8; ++j) v[j] = 0.f;
      #pragma unroll
      for (int t = 0; t < TT; ++t) {
        uint32_t m = 0;
        #pragma unroll
        for (int j = 0; j < 8; ++j) {
          const float cur = acc[t][j] + bias_s[obase + oc * 8 + j];
          const float vn = (v[j] + cur) * 0.5f;
          const bool s = vn >= 1.0f;
          m |= (uint32_t)s << j;
          v[j] = s ? 0.0f : vn;
        }
        if (m) {
          const int byi = (obase >> 3) + oc;
          s_out[(size_t)(b * 8 + t) * (O / 8) + byi] = (uint8_t)m;
          atomicOr(flg_next, 1u << (byi >> 3));
        }
      }
    } else {
      float oacc[8];
      #pragma unroll
      for (int j = 0; j < 8; ++j) oacc[j] = 0.f;
      #pragma unroll
      for (int t = 0; t < TT; ++t)
        #pragma unroll
        for (int j = 0; j < 8; ++j) oacc[j] += acc[t][j];
      float4 o0, o1;
      o0.x = oacc[0] * 0.125f + bias_s[oc * 8 + 0];
      o0.y = oacc[1] * 0.125f + bias_s[oc * 8 + 1];
      o0.z = oacc[2] * 0.125f + bias_s[oc * 8 + 2];
      o0.w = oacc[3] * 0.125f + bias_s[oc * 8 + 3];
      o1.x = oacc[4] * 0.125f + bias_s[oc * 8 + 4];
      o1.y = oacc[5] * 0.125f + bias_s[oc * 8 + 5];
      o1.z = oacc[6] * 0.125f + bias_s[oc * 8 + 6];
      o1.w = oacc[7] * 0.125f + bias_s[oc * 8 + 7];
      float* op = &outp[(size_t)(bglob0 + b) * 64 + oc * 8];
      *reinterpret_cast<float4*>(op)     = o0;
      *reinterpret_cast<float4*>(op + 4) = o1;
    }
  }
}

// LDS byte-offset map (total 36880 B -> 4 blocks/CU):
//   [0,17408)      wstage: L1 B-tiles (bf16, 32 rows x 33 lines x 16B) /
//                  L2-4 f32 wbuf 64x68
//   [17408,18432)  bias_s (256 f32)
//   [18432,22528)  s0 bits  [256 rows][4 u32]  (encoder out, L1 A-source)
//   [22528,30720)  s1 bits  [256 rows][16 u16] (L1 out)
//   [30720,34816)  s2 bits  [256 rows][4 u32]
//   [34816,36864)  s3 bits  [256 rows][2 u32]
//   [36864,36880)  flags: flg[0]=s1 chunk mask, flg[1]=s2, flg[2]=s3
__global__ void __launch_bounds__(NTHR, 4)
snn_fused(const float* __restrict__ x,
          const float* __restrict__ W1, const float* __restrict__ B1,
          const float* __restrict__ W2, const float* __restrict__ B2,
          const float* __restrict__ W3, const float* __restrict__ B3,
          const float* __restrict__ W4, const float* __restrict__ B4,
          float* __restrict__ out)
{
  __shared__ __align__(16) uint8_t smem[36880];
  float*    wstage = (float*)smem;
  uint16_t* B_lds  = (uint16_t*)smem;
  float*    bias_s = (float*)(smem + 17408);
  uint32_t* s0     = (uint32_t*)(smem + 18432);
  uint16_t* s1     = (uint16_t*)(smem + 22528);
  uint8_t*  s2     = smem + 30720;
  uint8_t*  s3     = smem + 34816;
  uint32_t* flg    = (uint32_t*)(smem + 36864);

  const int tid = threadIdx.x;
  const int lane = tid & 63, wid = tid >> 6;
  const int bglob0 = blockIdx.x * SPB;

  // zero s1..s3 + flags (spike writes are nonzero-predicated)
  for (int i = tid; i < (36880 - 22528) / 4; i += NTHR)
    ((uint32_t*)(smem + 22528))[i] = 0;

  // Poisson encoder, original JAX threefry stream: flat element i<2^24 takes
  // o0 of threefry(key,(i, i+2^24)); i>=2^24 takes o1. Per-t stride 2^22 =>
  // (t,b,d) pairs with (t+4,b,d). p = sigmoid(x) in f64.
  {
    const int b = tid >> 3, w16 = tid & 7;
    const int gb = bglob0 + b;
    uint32_t m[TT] = {0, 0, 0, 0, 0, 0, 0, 0};
    for (int j = 0; j < 16; ++j) {
      const int d = w16 * 16 + j;
      const double xv = (double)x[(size_t)gb * 128 + d];
      const double p = 1.0 / (1.0 + exp(-xv));
      #pragma unroll
      for (int t = 0; t < 4; ++t) {
        const uint32_t e = ((uint32_t)t << 22) | ((uint32_t)gb << 7) | (uint32_t)d;
        uint32_t o0, o1;
        threefry2x32(0u, 42u, e, e + 0x01000000u, o0, o1);
        const double u0 = (double)(__uint_as_float((o0 >> 9) | 0x3f800000u) - 1.0f);
        const double u1 = (double)(__uint_as_float((o1 >> 9) | 0x3f800000u) - 1.0f);
        m[t]     |= (uint32_t)(u0 < p) << j;
        m[t + 4] |= (uint32_t)(u1 < p) << j;
      }
    }
    #pragma unroll
    for (int t = 0; t < TT; ++t)
      ((uint16_t*)s0)[(b * 8 + t) * 8 + w16] = (uint16_t)m[t];
  }
  if (tid < 256) bias_s[tid] = B1[tid];
  __syncthreads();

  // ---- Layer 1 via MFMA (bf16 hi/lo split, K-stacked) ----
  // A-frags (spikes as bf16 {0,1}) built once from s0 bits; nchunk-invariant.
  // afrag[m][s]: M-tile m (rows wid*64+m*16+(lane&15)), k = 32s+(lane>>4)*8+j.
  short8 afrag[4][4];
  #pragma unroll
  for (int m = 0; m < 4; ++m) {
    const int row = wid * 64 + m * 16 + (lane & 15);
    #pragma unroll
    for (int s = 0; s < 4; ++s) {
      const uint32_t byte = (s0[row * 4 + s] >> ((lane >> 4) * 8)) & 0xffu;
      short8 a;
      #pragma unroll
      for (int j = 0; j < 8; ++j)
        a[j] = (short)(((byte >> j) & 1u) ? 0x3F80 : 0);
      afrag[m][s] = a;
    }
  }

  for (int nc = 0; nc < 8; ++nc) {
    __syncthreads();   // previous nchunk's B reads done
    // stage W1 cols [nc*32, nc*32+32), hi (sp=0..3) + lo (sp=4..7):
    // line(sp,g) = (sp*4+g)*33 + col holds 8 bf16 of k=32*(sp&3)+8g+j
    {
      const int col = tid >> 3, kq = tid & 7;
      const float* wsrc = &W1[(size_t)(nc * 32 + col) * 128 + kq * 16];
      float4 f[4];
      #pragma unroll
      for (int k = 0; k < 4; ++k)
        f[k] = *reinterpret_cast<const float4*>(wsrc + k * 4);
      #pragma unroll
      for (int h = 0; h < 2; ++h) {
        const int k0 = kq * 16 + h * 8;
        const int sp = k0 >> 5, g = (k0 >> 3) & 3;
        short8 hv, lv;
        #pragma unroll
        for (int e = 0; e < 8; ++e) {
          const float w = ((const float*)&f[2 * h])[e];  // f[2h],f[2h+1] contiguous
          const uint16_t hb = bf16_rne(w);
          const uint16_t lb = bf16_rne(w - bf16_f32(hb));
          hv[e] = (short)hb; lv[e] = (short)lb;
        }
        *(short8*)(B_lds + ((sp * 4 + g) * 33 + col) * 8)       = hv;
        *(short8*)(B_lds + (((sp + 4) * 4 + g) * 33 + col) * 8) = lv;
      }
    }
    __syncthreads();
    // MFMA: per wave 4 M-tiles x 2 N-tiles x 8 k'-steps (hi+lo in one chain)
    f32x4 C[4][2];
    #pragma unroll
    for (int m = 0; m < 4; ++m)
      #pragma unroll
      for (int nt = 0; nt < 2; ++nt)
        C[m][nt] = (f32x4){0.f, 0.f, 0.f, 0.f};
    #pragma unroll
    for (int nt = 0; nt < 2; ++nt)
      #pragma unroll
      for (int sp = 0; sp < 8; ++sp) {
        const short8 bf = *(const short8*)(
            B_lds + ((sp * 4 + (lane >> 4)) * 33 + nt * 16 + (lane & 15)) * 8);
        #pragma unroll
        for (int m = 0; m < 4; ++m)
          C[m][nt] = __builtin_amdgcn_mfma_f32_16x16x32_bf16(
              afrag[m][sp & 3], bf, C[m][nt], 0, 0, 0);
      }
    // LIF in-register. C row ρ=(lane>>4)*4+reg: group g=lane>>4:
    // sample b_off=g>>1, t=(g&1)*4+reg. v crosses t3->t4 via shfl_xor(16).
    const int g = lane >> 4;
    #pragma unroll
    for (int m = 0; m < 4; ++m)
      #pragma unroll
      for (int nt = 0; nt < 2; ++nt) {
        const float bb = bias_s[nc * 32 + nt * 16 + (lane & 15)];
        float v = 0.f; uint32_t nib = 0;
        #pragma unroll
        for (int r = 0; r < 4; ++r) {
          const float vn = (v + (C[m][nt][r] + bb)) * 0.5f;
          const bool s = vn >= 1.0f;
          nib |= (uint32_t)s << r;
          v = s ? 0.f : vn;
        }
        const float v3 = __shfl_xor(v, 16);
        if (g & 1) {   // upper-t lanes redo with true v after t=3
          v = v3; nib = 0;
          #pragma unroll
          for (int r = 0; r < 4; ++r) {
            const float vn = (v + (C[m][nt][r] + bb)) * 0.5f;
            const bool s = vn >= 1.0f;
            nib |= (uint32_t)s << r;
            v = s ? 0.f : vn;
          }
        }
        #pragma unroll
        for (int r = 0; r < 4; ++r) {
          const unsigned long long bal = __ballot((nib >> r) & 1u);
          if ((lane & 15) == 0) {
            const uint16_t w16v = (uint16_t)((bal >> (g * 16)) & 0xffffu);
            if (w16v) {
              const int row = (wid * 8 + m * 2 + (g >> 1)) * 8 + (g & 1) * 4 + r;
              const int wds = nc * 2 + nt;
              s1[row * 16 + wds] = w16v;
              atomicOr(&flg[0], 1u << (wds >> 2));
            }
          }
        }
      }
  }

  // ---- Layers 2..4 (VALU path, flag-gated; usually near-free) ----
  __syncthreads();
  const uint32_t m1 = flg[0];
  layer_valu<256, 128, false>(W2, B2, (const uint32_t*)s1, s2, &flg[1],
                              wstage, bias_s, nullptr, bglob0, m1);
  __syncthreads();
  const uint32_t m2 = flg[1];
  layer_valu<128, 64, false>(W3, B3, (const uint32_t*)s2, s3, &flg[2],
                             wstage, bias_s, nullptr, bglob0, m2);
  __syncthreads();
  const uint32_t m3 = flg[2];
  if (m3) {
    layer_valu<64, 64, true>(W4, B4, (const uint32_t*)s3, nullptr, nullptr,
                             wstage, bias_s, out, bglob0, m3);
  } else {
    // silent: out rows are exactly b4
    const int b = tid >> 3, oc = tid & 7;
    const float4 b0 = *reinterpret_cast<const float4*>(&B4[oc * 8]);
    const float4 b1 = *reinterpret_cast<const float4*>(&B4[oc * 8 + 4]);
    float* op = &out[(size_t)(bglob0 + b) * 64 + oc * 8];
    *reinterpret_cast<float4*>(op)     = b0;
    *reinterpret_cast<float4*>(op + 4) = b1;
  }
}

extern "C" void kernel_launch(void* const* d_in, const int* in_sizes, int n_in,
                              void* d_out, int out_size, void* d_ws, size_t ws_size,
                              hipStream_t stream) {
  const float* x  = (const float*)d_in[0];
  const float* W1 = (const float*)d_in[1];
  const float* B1 = (const float*)d_in[2];
  const float* W2 = (const float*)d_in[3];
  const float* B2 = (const float*)d_in[4];
  const float* W3 = (const float*)d_in[5];
  const float* B3 = (const float*)d_in[6];
  const float* W4 = (const float*)d_in[7];
  const float* B4 = (const float*)d_in[8];
  float* out = (float*)d_out;
  dim3 grid(32768 / SPB), block(NTHR);
  hipLaunchKernelGGL(snn_fused, grid, block, 0, stream,
                     x, W1, B1, W2, B2, W3, B3, W4, B4, out);
}